// Round 4
// baseline (271.065 us; speedup 1.0000x reference)
//
#include <hip/hip_runtime.h>
#include <hip/hip_bf16.h>

typedef __attribute__((ext_vector_type(8))) short bf16x8;
typedef __attribute__((ext_vector_type(4))) float f32x4;

// ---------------- fp32 -> bf16 conversion (8 elems/thread) ----------------
struct bf16x8_s { __hip_bfloat16 h[8]; };
struct bf16x4_s { __hip_bfloat16 h[4]; };

__global__ void cvt_kernel(const float* __restrict__ in,
                           __hip_bfloat16* __restrict__ out, int n8) {
  int i = blockIdx.x * blockDim.x + threadIdx.x;
  if (i >= n8) return;
  const float4* p = reinterpret_cast<const float4*>(in) + (size_t)i * 2;
  float4 a = p[0], b = p[1];
  bf16x8_s o;
  o.h[0] = __float2bfloat16(a.x); o.h[1] = __float2bfloat16(a.y);
  o.h[2] = __float2bfloat16(a.z); o.h[3] = __float2bfloat16(a.w);
  o.h[4] = __float2bfloat16(b.x); o.h[5] = __float2bfloat16(b.y);
  o.h[6] = __float2bfloat16(b.z); o.h[7] = __float2bfloat16(b.w);
  *reinterpret_cast<bf16x8_s*>(out + (size_t)i * 8) = o;
}

// ---------------- bf16 GEMM: C[M,N] = A[M,K] @ W[N,K]^T + bias -------------
// MODE 0: bf16 row-major. MODE 1: bf16 V-transpose. MODE 2: fp32 row-major.
// MODE 3: bf16 row-major scaled by 0.125*log2(e) (Q for exp2-domain softmax).
template <int MODE>
__global__ __launch_bounds__(256) void gemm_bt(
    const __hip_bfloat16* __restrict__ A, const __hip_bfloat16* __restrict__ W,
    const float* __restrict__ bias, void* __restrict__ Cout, int M, int N,
    int K) {
  constexpr int BM = 128, BN = 128, BK = 64;
  __shared__ __hip_bfloat16 As[BM][BK];
  __shared__ __hip_bfloat16 Ws[BN][BK];
  const int tid = threadIdx.x;
  const int lane = tid & 63;
  const int lrow = lane & 15;
  const int lhi = lane >> 4;
  const int lk8 = lhi * 8;
  const int wid = tid >> 6;
  const int wm = wid >> 1, wn = wid & 1;
  const int row0 = blockIdx.x * BM, col0 = blockIdx.y * BN;

  f32x4 acc[4][4] = {};

  for (int k0 = 0; k0 < K; k0 += BK) {
#pragma unroll
    for (int c = 0; c < 4; ++c) {
      const int e = (c * 256 + tid) * 8;
      const int eb = (c * 256 + (tid & 192)) * 8;
      const int r = e >> 6, cc = e & 63;
      __builtin_amdgcn_global_load_lds(
          (const __attribute__((address_space(1))) void*)(A + (size_t)(row0 + r) * K + k0 + cc),
          (__attribute__((address_space(3))) void*)(&As[0][0] + eb), 16, 0, 0);
    }
#pragma unroll
    for (int c = 0; c < 4; ++c) {
      const int e = (c * 256 + tid) * 8;
      const int eb = (c * 256 + (tid & 192)) * 8;
      const int r = e >> 6, cc = e & 63;
      __builtin_amdgcn_global_load_lds(
          (const __attribute__((address_space(1))) void*)(W + (size_t)(col0 + r) * K + k0 + cc),
          (__attribute__((address_space(3))) void*)(&Ws[0][0] + eb), 16, 0, 0);
    }
    __syncthreads();
#pragma unroll
    for (int kk = 0; kk < 2; ++kk) {
      bf16x8 af[4], bfr[4];
#pragma unroll
      for (int m = 0; m < 4; ++m)
        af[m] = *reinterpret_cast<const bf16x8*>(&As[wm * 64 + m * 16 + lrow][kk * 32 + lk8]);
#pragma unroll
      for (int n = 0; n < 4; ++n)
        bfr[n] = *reinterpret_cast<const bf16x8*>(&Ws[wn * 64 + n * 16 + lrow][kk * 32 + lk8]);
#pragma unroll
      for (int m = 0; m < 4; ++m)
#pragma unroll
        for (int n = 0; n < 4; ++n)
          acc[m][n] = __builtin_amdgcn_mfma_f32_16x16x32_bf16(af[m], bfr[n], acc[m][n], 0, 0, 0);
    }
    __syncthreads();
  }

  float bv[4];
#pragma unroll
  for (int n = 0; n < 4; ++n) bv[n] = bias[col0 + wn * 64 + n * 16 + lrow];

#pragma unroll
  for (int m = 0; m < 4; ++m) {
#pragma unroll
    for (int n = 0; n < 4; ++n) {
#pragma unroll
      for (int i = 0; i < 4; ++i) {
        const int row = row0 + wm * 64 + m * 16 + lhi * 4 + i;
        const int col = col0 + wn * 64 + n * 16 + lrow;
        const float v = acc[m][n][i] + bv[n];
        if constexpr (MODE == 0) {
          ((__hip_bfloat16*)Cout)[(size_t)row * N + col] = __float2bfloat16(v);
        } else if constexpr (MODE == 1) {
          const int t = row & 2047, b = row >> 11;
          const size_t idx =
              ((size_t)((b * 16 + (col >> 6)) * 64 + (col & 63))) * 2048 + t;
          ((__hip_bfloat16*)Cout)[idx] = __float2bfloat16(v);
        } else if constexpr (MODE == 2) {
          ((float*)Cout)[(size_t)row * N + col] = v;
        } else {
          ((__hip_bfloat16*)Cout)[(size_t)row * N + col] =
              __float2bfloat16(v * 0.18033688011112042f);
        }
      }
    }
  }
}

// ---------------- flash attention ------------------------------------------
// Block = 32 q-rows x 2 waves (KV-split by step parity), online softmax in
// exp2 domain (Q pre-scaled in GEMM epilogue), T13 defer-max, end-merge in
// LDS. Lane layout (swapped QK^T): lane holds S^T[.][q=lrow]; m/l replicated
// across the four lhi groups.
template <bool MASKED>
__device__ __forceinline__ void attn_step(
    int kv0, int q0, int lrow, int lhi, const __hip_bfloat16* __restrict__ Kb,
    const __hip_bfloat16* __restrict__ Vb, const bf16x8 qf[2][2], f32x4 o[2][4],
    float m[2], float l[2], __hip_bfloat16* __restrict__ P) {
  constexpr float TH = 8.0f;
  // ---- S^T = K @ Q^T (kf shared across the two q-fragments)
  f32x4 s[2][4] = {};
#pragma unroll
  for (int g = 0; g < 4; ++g)
#pragma unroll
    for (int kk = 0; kk < 2; ++kk) {
      bf16x8 kf = *reinterpret_cast<const bf16x8*>(
          Kb + (size_t)(kv0 + g * 16 + lrow) * 1024 + kk * 32 + lhi * 8);
#pragma unroll
      for (int j = 0; j < 2; ++j)
        s[j][g] = __builtin_amdgcn_mfma_f32_16x16x32_bf16(kf, qf[j][kk], s[j][g], 0, 0, 0);
    }
  // ---- optional mask + balanced-tree row max
  float mx[2];
#pragma unroll
  for (int j = 0; j < 2; ++j) {
    if (MASKED) {
#pragma unroll
      for (int g = 0; g < 4; ++g)
#pragma unroll
        for (int i = 0; i < 4; ++i) {
          const int k = kv0 + g * 16 + lhi * 4 + i;
          if (k > q0 + j * 16 + lrow) s[j][g][i] = -1e30f;
        }
    }
    float gm[4];
#pragma unroll
    for (int g = 0; g < 4; ++g)
      gm[g] = fmaxf(fmaxf(s[j][g][0], s[j][g][1]), fmaxf(s[j][g][2], s[j][g][3]));
    float t = fmaxf(fmaxf(gm[0], gm[1]), fmaxf(gm[2], gm[3]));
    t = fmaxf(t, __shfl_xor(t, 16));
    t = fmaxf(t, __shfl_xor(t, 32));
    mx[j] = t;
  }
  // ---- T13 defer-max
  const int need = (mx[0] > m[0] + TH) || (mx[1] > m[1] + TH);
  if (__any(need)) {
#pragma unroll
    for (int j = 0; j < 2; ++j) {
      const float nm = fmaxf(m[j], mx[j]);
      const float al = exp2f(m[j] - nm);
      m[j] = nm;
      l[j] *= al;
      float a4[4];
#pragma unroll
      for (int i = 0; i < 4; ++i) a4[i] = __shfl(al, 4 * lhi + i, 16);
#pragma unroll
      for (int f = 0; f < 4; ++f)
#pragma unroll
        for (int i = 0; i < 4; ++i) o[j][f][i] *= a4[i];
    }
  }
  // ---- P = exp2(s - m), tree row-sum, P[q][k] -> LDS (stride 72)
#pragma unroll
  for (int j = 0; j < 2; ++j) {
    float gs[4];
#pragma unroll
    for (int g = 0; g < 4; ++g) {
      bf16x4_s t4;
      float p0 = exp2f(s[j][g][0] - m[j]);
      float p1 = exp2f(s[j][g][1] - m[j]);
      float p2 = exp2f(s[j][g][2] - m[j]);
      float p3 = exp2f(s[j][g][3] - m[j]);
      t4.h[0] = __float2bfloat16(p0); t4.h[1] = __float2bfloat16(p1);
      t4.h[2] = __float2bfloat16(p2); t4.h[3] = __float2bfloat16(p3);
      gs[g] = (p0 + p1) + (p2 + p3);
      *reinterpret_cast<bf16x4_s*>(P + (j * 16 + lrow) * 72 + g * 16 + lhi * 4) = t4;
    }
    float sum = (gs[0] + gs[1]) + (gs[2] + gs[3]);
    sum += __shfl_xor(sum, 16);
    sum += __shfl_xor(sum, 32);
    l[j] += sum;
  }
  // ---- read P as A-fragments, O += P V (vf shared across fragments)
  bf16x8 pf[2][2];
#pragma unroll
  for (int j = 0; j < 2; ++j)
#pragma unroll
    for (int n = 0; n < 2; ++n)
      pf[j][n] = *reinterpret_cast<const bf16x8*>(P + (j * 16 + lrow) * 72 + n * 32 + lhi * 8);
#pragma unroll
  for (int n = 0; n < 2; ++n)
#pragma unroll
    for (int f = 0; f < 4; ++f) {
      bf16x8 vf = *reinterpret_cast<const bf16x8*>(
          Vb + (size_t)(f * 16 + lrow) * 2048 + kv0 + n * 32 + lhi * 8);
#pragma unroll
      for (int j = 0; j < 2; ++j)
        o[j][f] = __builtin_amdgcn_mfma_f32_16x16x32_bf16(pf[j][n], vf, o[j][f], 0, 0, 0);
    }
}

__global__ __launch_bounds__(128) void attn_fwd(
    const __hip_bfloat16* __restrict__ Q, const __hip_bfloat16* __restrict__ Km,
    const __hip_bfloat16* __restrict__ Vt, __hip_bfloat16* __restrict__ Y) {
  constexpr int T = 2048, C = 1024, D = 64;
  const int tid = threadIdx.x;
  const int wid = tid >> 6;
  const int lane = tid & 63;
  const int lrow = lane & 15;
  const int lhi = lane >> 4;
  // XCD-ownership swizzle: XCD (n&7) owns bh in [xcd*8, xcd*8+8) for the whole
  // kernel (K+V working set 8*512KB = 4MB = one XCD's L2). Heavy q-tiles first.
  const int n = blockIdx.x;
  const int xcd = n & 7;
  const int w = n >> 3;
  const int bh = xcd * 8 + (w & 7);
  const int qt = 63 - (w >> 3);
  const int b = bh >> 4, h = bh & 15;
  const int q0 = qt * 32;

  const __hip_bfloat16* Qb = Q + ((size_t)b * T) * C + h * D;
  const __hip_bfloat16* Kb = Km + ((size_t)b * T) * C + h * D;
  const __hip_bfloat16* Vb = Vt + (size_t)bh * D * T;

  // LDS: per-wave P [2][16][72] bf16 (4608 B each); end-merge area overlays it.
  __shared__ unsigned char smem[9216];
  __hip_bfloat16* P = (__hip_bfloat16*)(smem + wid * 4608);
  float* Osm = (float*)smem;            // 32 x 64 f32 (8192 B)
  float* Msm = (float*)(smem + 8192);   // 32 f32
  float* Lsm = (float*)(smem + 8320);   // 32 f32

  bf16x8 qf[2][2];
#pragma unroll
  for (int j = 0; j < 2; ++j)
#pragma unroll
    for (int kk = 0; kk < 2; ++kk)
      qf[j][kk] = *reinterpret_cast<const bf16x8*>(
          Qb + (size_t)(q0 + j * 16 + lrow) * C + kk * 32 + lhi * 8);

  f32x4 o[2][4] = {};
  float m[2] = {-1e30f, -1e30f}, l[2] = {0.f, 0.f};

  // KV-split: wave `wid` takes steps of parity wid; masked step by parity.
  const int full_end = ((q0 + 1) >> 6) << 6;  // start of the masked step
  for (int kv0 = wid * 64; kv0 < full_end; kv0 += 128)
    attn_step<false>(kv0, q0, lrow, lhi, Kb, Vb, qf, o, m, l, P);
  if (((full_end >> 6) & 1) == wid)
    attn_step<true>(full_end, q0, lrow, lhi, Kb, Vb, qf, o, m, l, P);

  // ---- merge the two waves' partial (m, l, O)
  __syncthreads();
  if (wid == 1) {
#pragma unroll
    for (int j = 0; j < 2; ++j) {
#pragma unroll
      for (int f = 0; f < 4; ++f)
#pragma unroll
        for (int i = 0; i < 4; ++i)
          Osm[(j * 16 + 4 * lhi + i) * 64 + f * 16 + lrow] = o[j][f][i];
      if (lhi == 0) { Msm[j * 16 + lrow] = m[j]; Lsm[j * 16 + lrow] = l[j]; }
    }
  }
  __syncthreads();
  if (wid == 0) {
#pragma unroll
    for (int j = 0; j < 2; ++j) {
      float m0r[4], l0r[4];
#pragma unroll
      for (int i = 0; i < 4; ++i) {
        m0r[i] = __shfl(m[j], 4 * lhi + i, 16);
        l0r[i] = __shfl(l[j], 4 * lhi + i, 16);
      }
#pragma unroll
      for (int i = 0; i < 4; ++i) {
        const int r = j * 16 + 4 * lhi + i;
        const float m1 = Msm[r], l1 = Lsm[r];
        const float mm = fmaxf(m0r[i], m1);
        const float a0 = exp2f(m0r[i] - mm);
        const float a1 = exp2f(m1 - mm);
        const float linv = 1.0f / (l0r[i] * a0 + l1 * a1);
        const int row = q0 + r;
#pragma unroll
        for (int f = 0; f < 4; ++f) {
          const float v =
              (o[j][f][i] * a0 + Osm[r * 64 + f * 16 + lrow] * a1) * linv;
          Y[((size_t)b * T + row) * C + h * D + f * 16 + lrow] = __float2bfloat16(v);
        }
      }
    }
  }
}

// ---------------- host launch ----------------------------------------------
extern "C" void kernel_launch(void* const* d_in, const int* in_sizes, int n_in,
                              void* d_out, int out_size, void* d_ws,
                              size_t ws_size, hipStream_t stream) {
  const float* x = (const float*)d_in[0];
  const float* Wq = (const float*)d_in[1];
  const float* bq = (const float*)d_in[2];
  const float* Wk = (const float*)d_in[3];
  const float* bk = (const float*)d_in[4];
  const float* Wv = (const float*)d_in[5];
  const float* bv = (const float*)d_in[6];
  const float* Wp = (const float*)d_in[7];
  const float* bp = (const float*)d_in[8];
  float* out = (float*)d_out;

  __hip_bfloat16* ws = (__hip_bfloat16*)d_ws;
  __hip_bfloat16* xb = ws;                   // 8388608
  __hip_bfloat16* wqb = xb + 8388608;        // 1048576
  __hip_bfloat16* wkb = wqb + 1048576;
  __hip_bfloat16* wvb = wkb + 1048576;
  __hip_bfloat16* wpb = wvb + 1048576;
  __hip_bfloat16* Qs = wpb + 1048576;        // 8388608
  __hip_bfloat16* Ks = Qs + 8388608;
  __hip_bfloat16* Vts = Ks + 8388608;        // V^T: [B*H*64][2048]
  __hip_bfloat16* Ys = Vts + 8388608;        // attn out [B*T][C]

  cvt_kernel<<<4096, 256, 0, stream>>>(x, xb, 1048576);
  cvt_kernel<<<512, 256, 0, stream>>>(Wq, wqb, 131072);
  cvt_kernel<<<512, 256, 0, stream>>>(Wk, wkb, 131072);
  cvt_kernel<<<512, 256, 0, stream>>>(Wv, wvb, 131072);
  cvt_kernel<<<512, 256, 0, stream>>>(Wp, wpb, 131072);

  dim3 g(8192 / 128, 1024 / 128);
  gemm_bt<3><<<g, 256, 0, stream>>>(xb, wqb, bq, Qs, 8192, 1024, 1024);
  gemm_bt<0><<<g, 256, 0, stream>>>(xb, wkb, bk, Ks, 8192, 1024, 1024);
  gemm_bt<1><<<g, 256, 0, stream>>>(xb, wvb, bv, Vts, 8192, 1024, 1024);

  attn_fwd<<<dim3(4096), 128, 0, stream>>>(Qs, Ks, Vts, Ys);

  gemm_bt<2><<<g, 256, 0, stream>>>(Ys, wpb, bp, out, 8192, 1024, 1024);
}

// Round 5
// 213.565 us; speedup vs baseline: 1.2692x; 1.2692x over previous
//
#include <hip/hip_runtime.h>
#include <hip/hip_bf16.h>

typedef __attribute__((ext_vector_type(8))) short bf16x8;
typedef __attribute__((ext_vector_type(4))) float f32x4;

// ---------------- fp32 -> bf16 conversion (8 elems/thread) ----------------
struct bf16x8_s { __hip_bfloat16 h[8]; };
struct bf16x4_s { __hip_bfloat16 h[4]; };

__global__ void cvt_kernel(const float* __restrict__ in,
                           __hip_bfloat16* __restrict__ out, int n8) {
  int i = blockIdx.x * blockDim.x + threadIdx.x;
  if (i >= n8) return;
  const float4* p = reinterpret_cast<const float4*>(in) + (size_t)i * 2;
  float4 a = p[0], b = p[1];
  bf16x8_s o;
  o.h[0] = __float2bfloat16(a.x); o.h[1] = __float2bfloat16(a.y);
  o.h[2] = __float2bfloat16(a.z); o.h[3] = __float2bfloat16(a.w);
  o.h[4] = __float2bfloat16(b.x); o.h[5] = __float2bfloat16(b.y);
  o.h[6] = __float2bfloat16(b.z); o.h[7] = __float2bfloat16(b.w);
  *reinterpret_cast<bf16x8_s*>(out + (size_t)i * 8) = o;
}

// ---------------- bf16 GEMM: C[M,N] = A[M,K] @ W[N,K]^T + bias -------------
// MODE 0: bf16 row-major. MODE 1: bf16 V-transpose. MODE 2: fp32 row-major.
// MODE 3: bf16 row-major scaled by 0.125*log2(e) (Q for exp2-domain softmax).
template <int MODE>
__global__ __launch_bounds__(256) void gemm_bt(
    const __hip_bfloat16* __restrict__ A, const __hip_bfloat16* __restrict__ W,
    const float* __restrict__ bias, void* __restrict__ Cout, int M, int N,
    int K) {
  constexpr int BM = 128, BN = 128, BK = 64;
  __shared__ __hip_bfloat16 As[BM][BK];
  __shared__ __hip_bfloat16 Ws[BN][BK];
  const int tid = threadIdx.x;
  const int lane = tid & 63;
  const int lrow = lane & 15;
  const int lhi = lane >> 4;
  const int lk8 = lhi * 8;
  const int wid = tid >> 6;
  const int wm = wid >> 1, wn = wid & 1;
  const int row0 = blockIdx.x * BM, col0 = blockIdx.y * BN;

  f32x4 acc[4][4] = {};

  for (int k0 = 0; k0 < K; k0 += BK) {
#pragma unroll
    for (int c = 0; c < 4; ++c) {
      const int e = (c * 256 + tid) * 8;
      const int eb = (c * 256 + (tid & 192)) * 8;
      const int r = e >> 6, cc = e & 63;
      __builtin_amdgcn_global_load_lds(
          (const __attribute__((address_space(1))) void*)(A + (size_t)(row0 + r) * K + k0 + cc),
          (__attribute__((address_space(3))) void*)(&As[0][0] + eb), 16, 0, 0);
    }
#pragma unroll
    for (int c = 0; c < 4; ++c) {
      const int e = (c * 256 + tid) * 8;
      const int eb = (c * 256 + (tid & 192)) * 8;
      const int r = e >> 6, cc = e & 63;
      __builtin_amdgcn_global_load_lds(
          (const __attribute__((address_space(1))) void*)(W + (size_t)(col0 + r) * K + k0 + cc),
          (__attribute__((address_space(3))) void*)(&Ws[0][0] + eb), 16, 0, 0);
    }
    __syncthreads();
#pragma unroll
    for (int kk = 0; kk < 2; ++kk) {
      bf16x8 af[4], bfr[4];
#pragma unroll
      for (int m = 0; m < 4; ++m)
        af[m] = *reinterpret_cast<const bf16x8*>(&As[wm * 64 + m * 16 + lrow][kk * 32 + lk8]);
#pragma unroll
      for (int n = 0; n < 4; ++n)
        bfr[n] = *reinterpret_cast<const bf16x8*>(&Ws[wn * 64 + n * 16 + lrow][kk * 32 + lk8]);
#pragma unroll
      for (int m = 0; m < 4; ++m)
#pragma unroll
        for (int n = 0; n < 4; ++n)
          acc[m][n] = __builtin_amdgcn_mfma_f32_16x16x32_bf16(af[m], bfr[n], acc[m][n], 0, 0, 0);
    }
    __syncthreads();
  }

  float bv[4];
#pragma unroll
  for (int n = 0; n < 4; ++n) bv[n] = bias[col0 + wn * 64 + n * 16 + lrow];

#pragma unroll
  for (int m = 0; m < 4; ++m) {
#pragma unroll
    for (int n = 0; n < 4; ++n) {
#pragma unroll
      for (int i = 0; i < 4; ++i) {
        const int row = row0 + wm * 64 + m * 16 + lhi * 4 + i;
        const int col = col0 + wn * 64 + n * 16 + lrow;
        const float v = acc[m][n][i] + bv[n];
        if constexpr (MODE == 0) {
          ((__hip_bfloat16*)Cout)[(size_t)row * N + col] = __float2bfloat16(v);
        } else if constexpr (MODE == 1) {
          const int t = row & 2047, b = row >> 11;
          const size_t idx =
              ((size_t)((b * 16 + (col >> 6)) * 64 + (col & 63))) * 2048 + t;
          ((__hip_bfloat16*)Cout)[idx] = __float2bfloat16(v);
        } else if constexpr (MODE == 2) {
          ((float*)Cout)[(size_t)row * N + col] = v;
        } else {
          ((__hip_bfloat16*)Cout)[(size_t)row * N + col] =
              __float2bfloat16(v * 0.18033688011112042f);
        }
      }
    }
  }
}

// ---------------- flash attention ------------------------------------------
// Block = 4 waves x 32 q-rows = 128 q-rows, sharing double-buffered K/V LDS
// tiles (64 kv x 64 d each) staged with global_load_lds (linear LDS dest,
// inverse-XOR-swizzled global source; reads apply the same XOR -> <=2-way
// bank aliasing). 2-phase pipeline: stage(t+1) issued before compute(t);
// one vmcnt-drain barrier per tile. Swapped QK^T, exp2 domain (Q pre-scaled),
// T13 defer-max, T5 setprio around MFMA clusters.

__device__ __forceinline__ void stage_kv(char* __restrict__ smem, int buf,
                                         const __hip_bfloat16* __restrict__ Kb,
                                         const __hip_bfloat16* __restrict__ Vb,
                                         int kv0, int tid) {
  const int w = tid >> 6, l = tid & 63;
  char* base = smem + buf * 16384;
#pragma unroll
  for (int s = 0; s < 2; ++s) {
    const int c = s * 256 + w * 64 + l;
    const int row = c >> 3;
    const int scb = ((c & 7) << 4) ^ ((row & 7) << 4);
    __builtin_amdgcn_global_load_lds(
        (const __attribute__((address_space(1))) void*)(Kb + (size_t)(kv0 + row) * 1024 + (scb >> 1)),
        (__attribute__((address_space(3))) void*)(base + s * 4096 + w * 1024), 16, 0, 0);
  }
#pragma unroll
  for (int s = 0; s < 2; ++s) {
    const int c = s * 256 + w * 64 + l;
    const int row = c >> 3;
    const int scb = ((c & 7) << 4) ^ ((row & 7) << 4);
    __builtin_amdgcn_global_load_lds(
        (const __attribute__((address_space(1))) void*)(Vb + (size_t)row * 2048 + kv0 + (scb >> 1)),
        (__attribute__((address_space(3))) void*)(base + 8192 + s * 4096 + w * 1024), 16, 0, 0);
  }
}

template <bool MASKED>
__device__ __forceinline__ void attn_step(
    int kv0, int q0w, int lrow, int lhi, const char* __restrict__ kvb,
    const bf16x8 qf[2][2], f32x4 o[2][4], float m[2], float l[2],
    __hip_bfloat16* __restrict__ P) {
  constexpr float TH = 8.0f;
  const int xr = (lrow & 7) << 4;
  // ---- S^T = K @ Q^T from swizzled LDS (kf shared across both q-fragments)
  f32x4 s[2][4] = {};
  __builtin_amdgcn_s_setprio(1);
#pragma unroll
  for (int g = 0; g < 4; ++g) {
    const char* rowp = kvb + (g * 16 + lrow) * 128;
#pragma unroll
    for (int kk = 0; kk < 2; ++kk) {
      bf16x8 kf = *reinterpret_cast<const bf16x8*>(rowp + ((kk * 64 + lhi * 16) ^ xr));
#pragma unroll
      for (int j = 0; j < 2; ++j)
        s[j][g] = __builtin_amdgcn_mfma_f32_16x16x32_bf16(kf, qf[j][kk], s[j][g], 0, 0, 0);
    }
  }
  __builtin_amdgcn_s_setprio(0);
  // ---- optional mask + balanced-tree row max
  float mx[2];
#pragma unroll
  for (int j = 0; j < 2; ++j) {
    if (MASKED) {
#pragma unroll
      for (int g = 0; g < 4; ++g)
#pragma unroll
        for (int i = 0; i < 4; ++i) {
          const int k = kv0 + g * 16 + lhi * 4 + i;
          if (k > q0w + j * 16 + lrow) s[j][g][i] = -1e30f;
        }
    }
    float gm[4];
#pragma unroll
    for (int g = 0; g < 4; ++g)
      gm[g] = fmaxf(fmaxf(s[j][g][0], s[j][g][1]), fmaxf(s[j][g][2], s[j][g][3]));
    float t = fmaxf(fmaxf(gm[0], gm[1]), fmaxf(gm[2], gm[3]));
    t = fmaxf(t, __shfl_xor(t, 16));
    t = fmaxf(t, __shfl_xor(t, 32));
    mx[j] = t;
  }
  // ---- T13 defer-max
  const int need = (mx[0] > m[0] + TH) || (mx[1] > m[1] + TH);
  if (__any(need)) {
#pragma unroll
    for (int j = 0; j < 2; ++j) {
      const float nm = fmaxf(m[j], mx[j]);
      const float al = exp2f(m[j] - nm);
      m[j] = nm;
      l[j] *= al;
      float a4[4];
#pragma unroll
      for (int i = 0; i < 4; ++i) a4[i] = __shfl(al, 4 * lhi + i, 16);
#pragma unroll
      for (int f = 0; f < 4; ++f)
#pragma unroll
        for (int i = 0; i < 4; ++i) o[j][f][i] *= a4[i];
    }
  }
  // ---- P = exp2(s - m), tree row-sum, P[q][k] -> LDS (stride 72)
#pragma unroll
  for (int j = 0; j < 2; ++j) {
    float gs[4];
#pragma unroll
    for (int g = 0; g < 4; ++g) {
      bf16x4_s t4;
      float p0 = exp2f(s[j][g][0] - m[j]);
      float p1 = exp2f(s[j][g][1] - m[j]);
      float p2 = exp2f(s[j][g][2] - m[j]);
      float p3 = exp2f(s[j][g][3] - m[j]);
      t4.h[0] = __float2bfloat16(p0); t4.h[1] = __float2bfloat16(p1);
      t4.h[2] = __float2bfloat16(p2); t4.h[3] = __float2bfloat16(p3);
      gs[g] = (p0 + p1) + (p2 + p3);
      *reinterpret_cast<bf16x4_s*>(P + (j * 16 + lrow) * 72 + g * 16 + lhi * 4) = t4;
    }
    float sum = (gs[0] + gs[1]) + (gs[2] + gs[3]);
    sum += __shfl_xor(sum, 16);
    sum += __shfl_xor(sum, 32);
    l[j] += sum;
  }
  // ---- read P as A-fragments, O += P V from swizzled LDS
  bf16x8 pf[2][2];
#pragma unroll
  for (int j = 0; j < 2; ++j)
#pragma unroll
    for (int n = 0; n < 2; ++n)
      pf[j][n] = *reinterpret_cast<const bf16x8*>(P + (j * 16 + lrow) * 72 + n * 32 + lhi * 8);
  __builtin_amdgcn_s_setprio(1);
#pragma unroll
  for (int n = 0; n < 2; ++n)
#pragma unroll
    for (int f = 0; f < 4; ++f) {
      bf16x8 vf = *reinterpret_cast<const bf16x8*>(
          kvb + 8192 + (f * 16 + lrow) * 128 + ((n * 64 + lhi * 16) ^ xr));
#pragma unroll
      for (int j = 0; j < 2; ++j)
        o[j][f] = __builtin_amdgcn_mfma_f32_16x16x32_bf16(pf[j][n], vf, o[j][f], 0, 0, 0);
    }
  __builtin_amdgcn_s_setprio(0);
}

__global__ __launch_bounds__(256, 3) void attn_fwd(
    const __hip_bfloat16* __restrict__ Q, const __hip_bfloat16* __restrict__ Km,
    const __hip_bfloat16* __restrict__ Vt, __hip_bfloat16* __restrict__ Y) {
  constexpr int T = 2048, C = 1024, D = 64;
  const int tid = threadIdx.x;
  const int wid = tid >> 6;
  const int lane = tid & 63;
  const int lrow = lane & 15;
  const int lhi = lane >> 4;
  // XCD-ownership swizzle: XCD (n&7) owns bh in [xcd*8, xcd*8+8); heavy
  // q-tiles dispatch first.
  const int n = blockIdx.x;
  const int xcd = n & 7;
  const int w8 = n >> 3;
  const int bh = xcd * 8 + (w8 & 7);
  const int qt = 15 - (w8 >> 3);
  const int b = bh >> 4, h = bh & 15;
  const int q0w = qt * 128 + wid * 32;

  const __hip_bfloat16* Qb = Q + ((size_t)b * T) * C + h * D;
  const __hip_bfloat16* Kb = Km + ((size_t)b * T) * C + h * D;
  const __hip_bfloat16* Vb = Vt + (size_t)bh * D * T;

  // LDS: [2 buf][K 8KB | V 8KB] = 32 KB, then per-wave P (stride-72) 4x4608 B.
  __shared__ char smem[51200];
  __hip_bfloat16* P = (__hip_bfloat16*)(smem + 32768 + wid * 4608);

  bf16x8 qf[2][2];
#pragma unroll
  for (int j = 0; j < 2; ++j)
#pragma unroll
    for (int kk = 0; kk < 2; ++kk)
      qf[j][kk] = *reinterpret_cast<const bf16x8*>(
          Qb + (size_t)(q0w + j * 16 + lrow) * C + kk * 32 + lhi * 8);

  f32x4 o[2][4] = {};
  float m[2] = {-1e30f, -1e30f}, l[2] = {0.f, 0.f};

  const int nt = 2 * qt + 2;        // KV tiles the block must stream
  const int ns = (q0w >> 6) + 1;    // steps this wave computes (last masked)

  stage_kv(smem, 0, Kb, Vb, 0, tid);
  for (int t = 0; t < nt; ++t) {
    __syncthreads();  // drains stage-for-t loads (vmcnt) + retires t-1 reads
    if (t + 1 < nt) stage_kv(smem, (t + 1) & 1, Kb, Vb, (t + 1) * 64, tid);
    if (t < ns) {
      const char* kvb = smem + (t & 1) * 16384;
      if (t == ns - 1)
        attn_step<true>(t * 64, q0w, lrow, lhi, kvb, qf, o, m, l, P);
      else
        attn_step<false>(t * 64, q0w, lrow, lhi, kvb, qf, o, m, l, P);
    }
  }

  // ---- normalize + store
#pragma unroll
  for (int j = 0; j < 2; ++j) {
    float l4[4];
#pragma unroll
    for (int i = 0; i < 4; ++i) l4[i] = __shfl(l[j], 4 * lhi + i, 16);
#pragma unroll
    for (int f = 0; f < 4; ++f)
#pragma unroll
      for (int i = 0; i < 4; ++i) {
        const int row = q0w + j * 16 + 4 * lhi + i;
        Y[((size_t)b * T + row) * C + h * D + f * 16 + lrow] =
            __float2bfloat16(o[j][f][i] / l4[i]);
      }
  }
}

// ---------------- host launch ----------------------------------------------
extern "C" void kernel_launch(void* const* d_in, const int* in_sizes, int n_in,
                              void* d_out, int out_size, void* d_ws,
                              size_t ws_size, hipStream_t stream) {
  const float* x = (const float*)d_in[0];
  const float* Wq = (const float*)d_in[1];
  const float* bq = (const float*)d_in[2];
  const float* Wk = (const float*)d_in[3];
  const float* bk = (const float*)d_in[4];
  const float* Wv = (const float*)d_in[5];
  const float* bv = (const float*)d_in[6];
  const float* Wp = (const float*)d_in[7];
  const float* bp = (const float*)d_in[8];
  float* out = (float*)d_out;

  __hip_bfloat16* ws = (__hip_bfloat16*)d_ws;
  __hip_bfloat16* xb = ws;                   // 8388608
  __hip_bfloat16* wqb = xb + 8388608;        // 1048576
  __hip_bfloat16* wkb = wqb + 1048576;
  __hip_bfloat16* wvb = wkb + 1048576;
  __hip_bfloat16* wpb = wvb + 1048576;
  __hip_bfloat16* Qs = wpb + 1048576;        // 8388608
  __hip_bfloat16* Ks = Qs + 8388608;
  __hip_bfloat16* Vts = Ks + 8388608;        // V^T: [B*H*64][2048]
  __hip_bfloat16* Ys = Vts + 8388608;        // attn out [B*T][C]

  cvt_kernel<<<4096, 256, 0, stream>>>(x, xb, 1048576);
  cvt_kernel<<<512, 256, 0, stream>>>(Wq, wqb, 131072);
  cvt_kernel<<<512, 256, 0, stream>>>(Wk, wkb, 131072);
  cvt_kernel<<<512, 256, 0, stream>>>(Wv, wvb, 131072);
  cvt_kernel<<<512, 256, 0, stream>>>(Wp, wpb, 131072);

  dim3 g(8192 / 128, 1024 / 128);
  gemm_bt<3><<<g, 256, 0, stream>>>(xb, wqb, bq, Qs, 8192, 1024, 1024);
  gemm_bt<0><<<g, 256, 0, stream>>>(xb, wkb, bk, Ks, 8192, 1024, 1024);
  gemm_bt<1><<<g, 256, 0, stream>>>(xb, wvb, bv, Vts, 8192, 1024, 1024);

  attn_fwd<<<dim3(1024), 256, 0, stream>>>(Qs, Ks, Vts, Ys);

  gemm_bt<2><<<g, 256, 0, stream>>>(Ys, wpb, bp, out, 8192, 1024, 1024);
}